// Round 12
// baseline (80.938 us; speedup 1.0000x reference)
//
#include <hip/hip_runtime.h>
#include <math.h>

typedef _Float16 f16x8 __attribute__((ext_vector_type(8)));
typedef float    f32x4 __attribute__((ext_vector_type(4)));

// v_sin_f32 / v_cos_f32 take REVOLUTIONS: sin(pi*x) = v_sin(0.5*x).
// All arguments here are in [-0.5, 0.5] revolutions -> no range reduction.
__device__ __forceinline__ float sinpi_hw(float x) { return __builtin_amdgcn_sinf(0.5f * x); }
__device__ __forceinline__ float cospi_hw(float x) { return __builtin_amdgcn_cosf(0.5f * x); }

// Fourier (trigonometric) interpolation via MFMA:
//   ynew*4096 = c1^T Y c2 - s641*s642*W      (W = sum (-1)^(n1+n2) Y)
// ROUND 12: bisect-by-composition of PROVEN parts only. The cotangent-
//   addition formula (rounds 8-11) produced garbage coefficients for
//   reasons not identified after 3 rounds — dropped entirely.
//   Coefficient math = round 6's (passed): per-n angle subtraction
//     st = sin(pi*(x-n/64)) = sx*tc_n - cx*ts_n
//     ct = cos(pi*(x-n/64)) = cx*tc_n + sx*ts_n
//     c[n] = (-1)^n * s64 * ct * rcp(st)
//   every j independent (no serial rotation chains, round 7's latency
//   bottleneck). Singular only at n = nstar -> replaced by cfix computed
//   from the exact (Sterbenz) delta. fr==0 exact hit: s64=0, cfix=64.
//   Structure = round 7's (passed): Y^T f16 in LDS, A-fragments hoisted
//   to registers once, 8 mt-tiles of 16 points per wave, 512 pts/block.
//   NEW (minimal): the 64-entry (cos,sin) tab is register-cached with
//   plain float2 reads (16 B-side + 16 stage-B entries per lane,
//   constant-indexed) -> hot loop has ZERO LDS traffic.
// CRITICAL: all register arrays fully unrolled / constant-indexed
//   (rounds 2-3: any dynamic index -> scratch -> 200+ MB spill traffic).

__global__ __launch_bounds__(256, 3)
void fourier_interp_mfma(const float* __restrict__ y,
                         const float* __restrict__ xnew,
                         float* __restrict__ out)
{
    __shared__ __align__(16) _Float16 Yth[64 * 72];  // Y^T f16, pad 72
    __shared__ float2 tab[64];                       // (cos(pi*n/64), sin(pi*n/64))
    __shared__ float4 S1[512];                       // (sx, cx, s64, cfix) dim 1
    __shared__ float4 S2[512];                       // dim 2
    __shared__ int    NS1[512], NS2[512];            // nearest-grid index
    __shared__ float  Wpart[4];

    const int tid    = threadIdx.x;
    const int batch  = blockIdx.x >> 5;      // 32 blocks per batch
    const int seg    = blockIdx.x & 31;      // 512 points per block
    const int gpbase = (batch << 14) + (seg << 9);

    // ---- stage Y -> transposed f16, fold in signed sum for W ----
    float wsum = 0.0f;
    {
        const float4* srcY = (const float4*)(y + (batch << 12));
#pragma unroll
        for (int i = 0; i < 4; ++i) {
            const int f = tid + (i << 8);          // float4 index 0..1023
            const float4 v = srcY[f];
            const int k = f >> 4;                  // n1
            const int n = (f & 15) << 2;           // n2 base
            Yth[(n+0)*72 + k] = (_Float16)v.x;
            Yth[(n+1)*72 + k] = (_Float16)v.y;
            Yth[(n+2)*72 + k] = (_Float16)v.z;
            Yth[(n+3)*72 + k] = (_Float16)v.w;
            const float sv = (v.x - v.y) + (v.z - v.w);   // (+,-,+,-) over n2
            wsum += (k & 1) ? -sv : sv;                   // (-1)^n1
        }
    }
#pragma unroll
    for (int off = 32; off > 0; off >>= 1)
        wsum += __shfl_down(wsum, off, 64);
    if ((tid & 63) == 0) Wpart[tid >> 6] = wsum;

    // ---- per-point setups, two points per thread (round 7 verbatim) ----
#pragma unroll
    for (int sp = 0; sp < 2; ++sp) {
        const int idx = tid + (sp << 8);
        const float2 xv = ((const float2*)xnew)[gpbase + idx];
        {
            const float x = xv.x;
            const float sx = sinpi_hw(x), cx = cospi_hw(x);
            const float g = x * 64.0f;           // exact
            const float jf = rintf(g);
            const float fr = g - jf;             // exact (Sterbenz)
            const int  ji = (int)jf;
            const float sf = sinpi_hw(fr);
            const float s64 = (ji & 1) ? -sf : sf;
            const float d = x - jf * 0.015625f;  // exact
            const float cf = (fr == 0.0f) ? 64.0f
                : sf * cospi_hw(d) * __builtin_amdgcn_rcpf(sinpi_hw(d));
            S1[idx]  = make_float4(sx, cx, s64, cf);
            NS1[idx] = ji & 63;
        }
        {
            const float x = xv.y;
            const float sx = sinpi_hw(x), cx = cospi_hw(x);
            const float g = x * 64.0f;
            const float jf = rintf(g);
            const float fr = g - jf;
            const int  ji = (int)jf;
            const float sf = sinpi_hw(fr);
            const float s64 = (ji & 1) ? -sf : sf;
            const float d = x - jf * 0.015625f;
            const float cf = (fr == 0.0f) ? 64.0f
                : sf * cospi_hw(d) * __builtin_amdgcn_rcpf(sinpi_hw(d));
            S2[idx]  = make_float4(sx, cx, s64, cf);
            NS2[idx] = ji & 63;
        }
    }
    if (tid < 64)
        tab[tid] = make_float2(cospi_hw((float)tid * (1.0f / 64.0f)),
                               sinpi_hw((float)tid * (1.0f / 64.0f)));
    __syncthreads();

    const float W = (Wpart[0] + Wpart[1]) + (Wpart[2] + Wpart[3]);

    const int lane = tid & 63;
    const int wv   = tid >> 6;
    const int quad = lane >> 4;
    const int lrow = lane & 15;

    // ---- hoist A-operand (Y^T) fragments: mt-invariant, read LDS ONCE ----
    f16x8 Ah[4][2];
#pragma unroll
    for (int nt = 0; nt < 4; ++nt)
#pragma unroll
        for (int kt = 0; kt < 2; ++kt) {
            const int off = ((nt << 4) + lrow) * 72 + (kt << 5) + (quad << 3);
            Ah[nt][kt] = *(const f16x8*)&Yth[off];   // ds_read_b128
        }

    // ---- register-cache this lane's tab entries (fixed across mt) ----
    float2 T1[2][8];                       // B-side: n1 = kt*32 + quad*8 + j
#pragma unroll
    for (int kt = 0; kt < 2; ++kt)
#pragma unroll
        for (int j = 0; j < 8; ++j)
            T1[kt][j] = tab[(kt << 5) + (quad << 3) + j];
    float2 T2[4][4];                       // stage-B: n2 = nt*16 + quad*4 + r
#pragma unroll
    for (int nt = 0; nt < 4; ++nt)
#pragma unroll
        for (int r = 0; r < 4; ++r)
            T2[nt][r] = tab[(nt << 4) + (quad << 2) + r];

    // ---- 8 tiles of 16 points per wave ----
#pragma unroll 1
    for (int mt = 0; mt < 8; ++mt) {
        const int mtbase = (wv << 7) + (mt << 4);   // local point base of tile
        const float4 s1 = S1[mtbase + lrow];        // (sx, cx, s64, cfix)
        const int n1fix = NS1[mtbase + lrow];

        f32x4 acc[4];
#pragma unroll
        for (int nt = 0; nt < 4; ++nt) acc[nt] = (f32x4){0.f, 0.f, 0.f, 0.f};

        // ---- per kt: build B fragment (C1 f16), then MFMA over nt ----
#pragma unroll
        for (int kt = 0; kt < 2; ++kt) {
            const int n1b = (kt << 5) + (quad << 3);
            f16x8 bv;
#pragma unroll
            for (int j = 0; j < 8; ++j) {           // parity(n1) == parity(j)
                const float tc = T1[kt][j].x;
                const float ts = T1[kt][j].y;
                const float st = s1.x * tc - s1.y * ts;  // sin(pi*(x-n/64))
                const float ct = s1.y * tc + s1.x * ts;  // cos(pi*(x-n/64))
                const float sgn = (j & 1) ? -s1.z : s1.z;
                float c = sgn * ct * __builtin_amdgcn_rcpf(st);
                c = (n1b + j == n1fix) ? s1.w : c;
                bv[j] = (_Float16)c;
            }
#pragma unroll
            for (int nt = 0; nt < 4; ++nt)
                acc[nt] = __builtin_amdgcn_mfma_f32_16x16x32_f16(Ah[nt][kt], bv, acc[nt], 0, 0, 0);
        }

        // ---- stage B: lane holds U[p=lrow][n2 = nt*16 + quad*4 + reg] ----
        const float4 s2 = S2[mtbase + lrow];
        const int n2fix = NS2[mtbase + lrow];
        float red = 0.0f;
#pragma unroll
        for (int nt = 0; nt < 4; ++nt) {
            const int n2b = (nt << 4) + (quad << 2);
#pragma unroll
            for (int reg = 0; reg < 4; ++reg) {      // parity(n2) == parity(reg)
                const float tc = T2[nt][reg].x;
                const float ts = T2[nt][reg].y;
                const float st = s2.x * tc - s2.y * ts;
                const float ct = s2.y * tc + s2.x * ts;
                const float sgn = (reg & 1) ? -s2.z : s2.z;
                float c = sgn * ct * __builtin_amdgcn_rcpf(st);
                c = (n2b + reg == n2fix) ? s2.w : c;
                red = fmaf(c, acc[nt][reg], red);
            }
        }
        red += __shfl_xor(red, 16, 64);   // reduce across quads (n2 blocks)
        red += __shfl_xor(red, 32, 64);
        if (lane < 16) {                   // writer owns its point's setups
            const float r = red - s1.z * s2.z * W;
            out[gpbase + mtbase + lane] = r * (1.0f / 4096.0f);
        }
    }
}

extern "C" void kernel_launch(void* const* d_in, const int* in_sizes, int n_in,
                              void* d_out, int out_size, void* d_ws, size_t ws_size,
                              hipStream_t stream)
{
    const float* y    = (const float*)d_in[0];   // [32, 64, 64]
    const float* xnew = (const float*)d_in[1];   // [32, 128, 128, 2]
    float* out        = (float*)d_out;           // [32, 128, 128]

    // 32 batches * 32 blocks of 512 points = 1024 blocks
    fourier_interp_mfma<<<1024, 256, 0, stream>>>(y, xnew, out);
}